// Round 14
// baseline (516.472 us; speedup 1.0000x reference)
//
#include <hip/hip_runtime.h>
#include <hip/hip_bf16.h>
#include <stdint.h>
#include <stddef.h>

// ClusterLayer: q = normalize_rows( 1 / (1 + ||z-c||^2) )
// N=200000 rows, D=256, KC=256 clusters. fp32 in/out; cross-term via bf16 MFMA.
// R13: de-convoy, resourced to fit. NT=512 (allocator gives clean 100-128 VGPR
// here; 1024-thr pins 64 and spills — R5/R6/R7 evidence). Each wave owns a
// full 16x256 tile: acc[16] (R1-proven), intra-wave row-normalize, NO in-loop
// barrier -> 2 waves/SIMD drift out of phase and cover each other's stalls
// (R12 showed pipes fully serialized under the per-tile barrier: serial-sum
// cycle model matched observed). Register diet vs R11: ring-2 (not 4), csq
// read from LDS only in the epilogue (not 16 live regs), cvt_pk conversion.

#define NT 512
#define GRID 256
#define WAVES (GRID * 8)   // 2048 free-running waves
#define D 256
#define KC 256

typedef __attribute__((ext_vector_type(8))) short short8;  // 8 bf16 (4 VGPRs)
typedef __attribute__((ext_vector_type(4))) float f32x4;   // MFMA accumulator

// fp32 -> bf16, round-to-nearest-even (branch-free) — prep kernels only
__device__ __forceinline__ short f2bf(float f) {
    uint32_t u = __builtin_bit_cast(uint32_t, f);
    u += 0x7FFFu + ((u >> 16) & 1u);
    return (short)(u >> 16);
}

// packed RNE f32x2 -> bf16x2 (emits v_cvt_pk_bf16_f32)
__device__ __forceinline__ unsigned int pk2(float a, float b) {
    __hip_bfloat162 h = __float22bfloat162_rn(make_float2(a, b));
    unsigned int r;
    __builtin_memcpy(&r, &h, 4);
    return r;
}

// csq[k] = ||c_k||^2 ; one wave per cluster row.
__global__ void prep_csq(const float* __restrict__ C, float* __restrict__ csq) {
    const int k = blockIdx.x;
    const int l = threadIdx.x;  // 0..63
    float4 v = *(const float4*)(C + k * D + l * 4);
    float s = v.x * v.x + v.y * v.y + v.z * v.z + v.w * v.w;
#pragma unroll
    for (int off = 32; off > 0; off >>= 1) s += __shfl_down(s, off);
    if (l == 0) csq[k] = s;
}

// Reorder C into MFMA-B fragment order, bf16 (verified R1-R12):
// Bf[((kk*16 + ct)*64 + lane)*8 + e] = bf16( C[(ct*16 + (lane&15))*D + kk*32 + (lane>>4)*8 + e] )
__global__ void prep_reorder(const float* __restrict__ C, unsigned short* __restrict__ Bf) {
    const int kk = blockIdx.x >> 4;   // 0..7
    const int ct = blockIdx.x & 15;   // 0..15
    const int lane = threadIdx.x;     // 0..63
    const int l15 = lane & 15;
    const int lg = lane >> 4;
    const float* src = C + (size_t)(ct * 16 + l15) * D + kk * 32 + lg * 8;
    float4 a0 = *(const float4*)(src);
    float4 a1 = *(const float4*)(src + 4);
    ushort4 p0, p1;
    p0.x = (unsigned short)f2bf(a0.x); p0.y = (unsigned short)f2bf(a0.y);
    p0.z = (unsigned short)f2bf(a0.z); p0.w = (unsigned short)f2bf(a0.w);
    p1.x = (unsigned short)f2bf(a1.x); p1.y = (unsigned short)f2bf(a1.y);
    p1.z = (unsigned short)f2bf(a1.z); p1.w = (unsigned short)f2bf(a1.w);
    unsigned short* dst = Bf + ((size_t)(kk * 16 + ct) * 64 + lane) * 8;
    *(ushort4*)(dst) = p0;
    *(ushort4*)(dst + 4) = p1;
}

__global__ void __launch_bounds__(NT)
main_kernel(const float* __restrict__ z,
            const uint4* __restrict__ Bf,
            const float* __restrict__ csq,
            float* __restrict__ out, int ntiles) {
    __shared__ uint4 ldsB[8192];   // 128KB fragment-ordered bf16 B
    __shared__ float ldsCsq[KC];   // 1KB ||c_k||^2 (read in epilogue only)

    const int tid  = threadIdx.x;
    const int lane = tid & 63;
    const int wave = tid >> 6;           // 0..7
    const int l15  = lane & 15;
    const int lg   = lane >> 4;          // 0..3

    // stage whole B + csq once; the ONLY barrier in the kernel.
#pragma unroll
    for (int i = 0; i < 16; ++i) ldsB[tid + i * NT] = Bf[tid + i * NT];
    if (tid < KC) ldsCsq[tid] = csq[tid];
    __syncthreads();

    const char* ldsb = (const char*)ldsB;
    const int laneoff = lane << 4;

    int t = blockIdx.x * 8 + wave;       // < 2048 <= ntiles: initially valid
    const float* zrow = z + (size_t)(t * 16 + l15) * D + lg * 8;
    // 2-deep rolling A pipeline, carried ACROSS tiles (R3/R9-proven pattern)
    float4 c0 = *(const float4*)(zrow),      c1 = *(const float4*)(zrow + 4);
    float4 d0 = *(const float4*)(zrow + 32), d1 = *(const float4*)(zrow + 36);

    while (true) {
        const int tn = t + WAVES;
        const bool more = tn < ntiles;
        const float* zrow_n = more ? z + (size_t)(tn * 16 + l15) * D + lg * 8 : zrow;

        f32x4 acc[16];
        const f32x4 zero4 = {0.f, 0.f, 0.f, 0.f};
#pragma unroll
        for (int ct = 0; ct < 16; ++ct) acc[ct] = zero4;
        float zsq_part = 0.f;

#pragma unroll
        for (int kk = 0; kk < 8; ++kk) {
            // prefetch 2 k-steps ahead; kk=6,7 fetch NEXT tile's k-steps 0,1
            const float* pf = (kk < 6) ? (zrow + (kk + 2) * 32) : (zrow_n + (kk - 6) * 32);
            float4 e0 = *(const float4*)(pf);
            float4 e1 = *(const float4*)(pf + 4);

            zsq_part += c0.x * c0.x + c0.y * c0.y + c0.z * c0.z + c0.w * c0.w +
                        c1.x * c1.x + c1.y * c1.y + c1.z * c1.z + c1.w * c1.w;
            // packed RNE conversion: 4x v_cvt_pk_bf16_f32
            uint4 u;
            u.x = pk2(c0.x, c0.y); u.y = pk2(c0.z, c0.w);
            u.z = pk2(c1.x, c1.y); u.w = pk2(c1.z, c1.w);
            short8 af;
            __builtin_memcpy(&af, &u, 16);
#pragma unroll
            for (int ct = 0; ct < 16; ++ct) {
                // linear per-lane address -> zero bank conflicts
                short8 bf = *(const short8*)(ldsb + laneoff + ((kk * 16 + ct) << 10));
                acc[ct] = __builtin_amdgcn_mfma_f32_16x16x32_bf16(af, bf, acc[ct], 0, 0, 0);
            }
            c0 = d0; c1 = d1; d0 = e0; d1 = e1;
        }
        // c/d now hold next tile's k-steps 0,1 (loads may still be in flight)

        // ||z_row||^2: lane holds partial for row l15; sum over the 4 lane-groups
        float zsq = zsq_part;
        zsq += __shfl_xor(zsq, 16);
        zsq += __shfl_xor(zsq, 32);
        float zsqj[4];
#pragma unroll
        for (int j = 0; j < 4; ++j) zsqj[j] = __shfl(zsq, lg * 4 + j);

        // q = 1/(1+dist); accumulate per-lane partial row sums.
        // csq read from LDS here (epilogue-local, not live across the kk-loop)
        float rs[4] = {0.f, 0.f, 0.f, 0.f};
#pragma unroll
        for (int ct = 0; ct < 16; ++ct) {
            const float cs = ldsCsq[ct * 16 + l15];
#pragma unroll
            for (int j = 0; j < 4; ++j) {
                float dist = zsqj[j] + cs - 2.0f * acc[ct][j];
                dist = fmaxf(dist, 0.f);
                float qv = 1.0f / (1.0f + dist);
                acc[ct][j] = qv;
                rs[j] += qv;
            }
        }
        // reduce row sums across the 16-lane column group (intra-wave)
#pragma unroll
        for (int j = 0; j < 4; ++j) {
            float s = rs[j];
            s += __shfl_xor(s, 1);
            s += __shfl_xor(s, 2);
            s += __shfl_xor(s, 4);
            s += __shfl_xor(s, 8);
            rs[j] = 1.0f / s;
        }
        // store: lane writes col ct*16+l15 of rows t*16 + lg*4 + j
#pragma unroll
        for (int j = 0; j < 4; ++j) {
            float* orow = out + (size_t)(t * 16 + lg * 4 + j) * KC + l15;
#pragma unroll
            for (int ct = 0; ct < 16; ++ct) orow[ct * 16] = acc[ct][j] * rs[j];
        }

        if (!more) break;
        t = tn;
        zrow = zrow_n;
    }
}

extern "C" void kernel_launch(void* const* d_in, const int* in_sizes, int n_in,
                              void* d_out, int out_size, void* d_ws, size_t ws_size,
                              hipStream_t stream) {
    const float* zp = (const float*)d_in[0];
    const float* Cp = (const float*)d_in[1];
    const int N = in_sizes[0] / D;  // 200000
    unsigned short* Bf = (unsigned short*)d_ws;                          // 128KB bf16 frag-ordered
    float* csq = (float*)((char*)d_ws + (size_t)KC * D * sizeof(unsigned short));  // 1KB

    prep_csq<<<KC, 64, 0, stream>>>(Cp, csq);
    prep_reorder<<<128, 64, 0, stream>>>(Cp, Bf);

    const int ntiles = (N + 15) / 16;  // 12500
    main_kernel<<<GRID, NT, 0, stream>>>(zp, (const uint4*)Bf, csq, (float*)d_out, ntiles);
}

// Round 15
// 111.312 us; speedup vs baseline: 4.6399x; 4.6399x over previous
//
#include <hip/hip_runtime.h>
#include <hip/hip_bf16.h>
#include <stdint.h>
#include <stddef.h>

// ClusterLayer: q = normalize_rows( 1 / (1 + ||z-c||^2) )
// N=200000 rows, D=256, KC=256 clusters. fp32 in/out; cross-term via bf16 MFMA.
// R14 = R13 (de-convoyed free-running waves: LDS-resident fragment-ordered B,
// one full 16x256 tile per wave, NO in-loop barrier) + inline-asm MFMA with
// "+a" constraint: acc[16] is FORCED into 64 AGPRs. This breaks the allocator
// behavior that killed R7/R11/R13 (with LDS-B it refuses AGPR placement and
// caps arch VGPRs at 128 -> acc spilled to scratch: 749MB fetch signature).
// Arch-VGPR side now ~70 (ring-2 + cvt_pk + addressing): no spill possible.

#define NT 512
#define GRID 256
#define WAVES (GRID * 8)   // 2048 free-running waves
#define D 256
#define KC 256

typedef __attribute__((ext_vector_type(8))) short short8;  // 8 bf16 (4 VGPRs)
typedef __attribute__((ext_vector_type(4))) float f32x4;   // MFMA accumulator

// fp32 -> bf16, round-to-nearest-even (branch-free) — prep kernels only
__device__ __forceinline__ short f2bf(float f) {
    uint32_t u = __builtin_bit_cast(uint32_t, f);
    u += 0x7FFFu + ((u >> 16) & 1u);
    return (short)(u >> 16);
}

// packed RNE f32x2 -> bf16x2 (emits v_cvt_pk_bf16_f32)
__device__ __forceinline__ unsigned int pk2(float a, float b) {
    __hip_bfloat162 h = __float22bfloat162_rn(make_float2(a, b));
    unsigned int r;
    __builtin_memcpy(&r, &h, 4);
    return r;
}

// csq[k] = ||c_k||^2 ; one wave per cluster row.
__global__ void prep_csq(const float* __restrict__ C, float* __restrict__ csq) {
    const int k = blockIdx.x;
    const int l = threadIdx.x;  // 0..63
    float4 v = *(const float4*)(C + k * D + l * 4);
    float s = v.x * v.x + v.y * v.y + v.z * v.z + v.w * v.w;
#pragma unroll
    for (int off = 32; off > 0; off >>= 1) s += __shfl_down(s, off);
    if (l == 0) csq[k] = s;
}

// Reorder C into MFMA-B fragment order, bf16 (verified R1-R13):
// Bf[((kk*16 + ct)*64 + lane)*8 + e] = bf16( C[(ct*16 + (lane&15))*D + kk*32 + (lane>>4)*8 + e] )
__global__ void prep_reorder(const float* __restrict__ C, unsigned short* __restrict__ Bf) {
    const int kk = blockIdx.x >> 4;   // 0..7
    const int ct = blockIdx.x & 15;   // 0..15
    const int lane = threadIdx.x;     // 0..63
    const int l15 = lane & 15;
    const int lg = lane >> 4;
    const float* src = C + (size_t)(ct * 16 + l15) * D + kk * 32 + lg * 8;
    float4 a0 = *(const float4*)(src);
    float4 a1 = *(const float4*)(src + 4);
    ushort4 p0, p1;
    p0.x = (unsigned short)f2bf(a0.x); p0.y = (unsigned short)f2bf(a0.y);
    p0.z = (unsigned short)f2bf(a0.z); p0.w = (unsigned short)f2bf(a0.w);
    p1.x = (unsigned short)f2bf(a1.x); p1.y = (unsigned short)f2bf(a1.y);
    p1.z = (unsigned short)f2bf(a1.z); p1.w = (unsigned short)f2bf(a1.w);
    unsigned short* dst = Bf + ((size_t)(kk * 16 + ct) * 64 + lane) * 8;
    *(ushort4*)(dst) = p0;
    *(ushort4*)(dst + 4) = p1;
}

__global__ void __launch_bounds__(NT)
main_kernel(const float* __restrict__ z,
            const uint4* __restrict__ Bf,
            const float* __restrict__ csq,
            float* __restrict__ out, int ntiles) {
    __shared__ uint4 ldsB[8192];   // 128KB fragment-ordered bf16 B
    __shared__ float ldsCsq[KC];   // 1KB ||c_k||^2 (read in epilogue only)

    const int tid  = threadIdx.x;
    const int lane = tid & 63;
    const int wave = tid >> 6;           // 0..7
    const int l15  = lane & 15;
    const int lg   = lane >> 4;          // 0..3

    // stage whole B + csq once; the ONLY barrier in the kernel.
#pragma unroll
    for (int i = 0; i < 16; ++i) ldsB[tid + i * NT] = Bf[tid + i * NT];
    if (tid < KC) ldsCsq[tid] = csq[tid];
    __syncthreads();

    const char* ldsb = (const char*)ldsB;
    const int laneoff = lane << 4;

    int t = blockIdx.x * 8 + wave;       // < 2048 <= ntiles: initially valid
    const float* zrow = z + (size_t)(t * 16 + l15) * D + lg * 8;
    // 2-deep rolling A pipeline, carried ACROSS tiles (R3/R9-proven pattern)
    float4 c0 = *(const float4*)(zrow),      c1 = *(const float4*)(zrow + 4);
    float4 d0 = *(const float4*)(zrow + 32), d1 = *(const float4*)(zrow + 36);

    while (true) {
        const int tn = t + WAVES;
        const bool more = tn < ntiles;
        const float* zrow_n = more ? z + (size_t)(tn * 16 + l15) * D + lg * 8 : zrow;

        // acc[16] pinned to AGPRs via "+a" asm constraint (64 AGPRs)
        f32x4 acc[16];
        const f32x4 zero4 = {0.f, 0.f, 0.f, 0.f};
#pragma unroll
        for (int ct = 0; ct < 16; ++ct) acc[ct] = zero4;
        float zsq_part = 0.f;

#pragma unroll
        for (int kk = 0; kk < 8; ++kk) {
            // prefetch 2 k-steps ahead; kk=6,7 fetch NEXT tile's k-steps 0,1
            const float* pf = (kk < 6) ? (zrow + (kk + 2) * 32) : (zrow_n + (kk - 6) * 32);
            float4 e0 = *(const float4*)(pf);
            float4 e1 = *(const float4*)(pf + 4);

            zsq_part += c0.x * c0.x + c0.y * c0.y + c0.z * c0.z + c0.w * c0.w +
                        c1.x * c1.x + c1.y * c1.y + c1.z * c1.z + c1.w * c1.w;
            // packed RNE conversion: 4x v_cvt_pk_bf16_f32
            uint4 u;
            u.x = pk2(c0.x, c0.y); u.y = pk2(c0.z, c0.w);
            u.z = pk2(c1.x, c1.y); u.w = pk2(c1.z, c1.w);
            short8 af;
            __builtin_memcpy(&af, &u, 16);
#pragma unroll
            for (int ct = 0; ct < 16; ++ct) {
                // linear per-lane address -> zero bank conflicts
                short8 bf = *(const short8*)(ldsb + laneoff + ((kk * 16 + ct) << 10));
                // D,C in AGPRs; A,B in VGPRs. Data deps tracked via constraints,
                // compiler inserts the needed lgkmcnt before each use of bf.
                asm("v_mfma_f32_16x16x32_bf16 %0, %1, %2, %0"
                    : "+a"(acc[ct])
                    : "v"(af), "v"(bf));
            }
            c0 = d0; c1 = d1; d0 = e0; d1 = e1;
        }
        // c/d now hold next tile's k-steps 0,1 (loads may still be in flight)

        // ||z_row||^2: lane holds partial for row l15; sum over the 4 lane-groups
        float zsq = zsq_part;
        zsq += __shfl_xor(zsq, 16);
        zsq += __shfl_xor(zsq, 32);
        float zsqj[4];
#pragma unroll
        for (int j = 0; j < 4; ++j) zsqj[j] = __shfl(zsq, lg * 4 + j);

        // q = 1/(1+dist); accumulate per-lane partial row sums.
        // csq read from LDS here (epilogue-local, not live across the kk-loop)
        float rs[4] = {0.f, 0.f, 0.f, 0.f};
#pragma unroll
        for (int ct = 0; ct < 16; ++ct) {
            const float cs = ldsCsq[ct * 16 + l15];
#pragma unroll
            for (int j = 0; j < 4; ++j) {
                float dist = zsqj[j] + cs - 2.0f * acc[ct][j];
                dist = fmaxf(dist, 0.f);
                float qv = 1.0f / (1.0f + dist);
                acc[ct][j] = qv;
                rs[j] += qv;
            }
        }
        // reduce row sums across the 16-lane column group (intra-wave)
#pragma unroll
        for (int j = 0; j < 4; ++j) {
            float s = rs[j];
            s += __shfl_xor(s, 1);
            s += __shfl_xor(s, 2);
            s += __shfl_xor(s, 4);
            s += __shfl_xor(s, 8);
            rs[j] = 1.0f / s;
        }
        // store: lane writes col ct*16+l15 of rows t*16 + lg*4 + j
#pragma unroll
        for (int j = 0; j < 4; ++j) {
            float* orow = out + (size_t)(t * 16 + lg * 4 + j) * KC + l15;
#pragma unroll
            for (int ct = 0; ct < 16; ++ct) orow[ct * 16] = acc[ct][j] * rs[j];
        }

        if (!more) break;
        t = tn;
        zrow = zrow_n;
    }
}

extern "C" void kernel_launch(void* const* d_in, const int* in_sizes, int n_in,
                              void* d_out, int out_size, void* d_ws, size_t ws_size,
                              hipStream_t stream) {
    const float* zp = (const float*)d_in[0];
    const float* Cp = (const float*)d_in[1];
    const int N = in_sizes[0] / D;  // 200000
    unsigned short* Bf = (unsigned short*)d_ws;                          // 128KB bf16 frag-ordered
    float* csq = (float*)((char*)d_ws + (size_t)KC * D * sizeof(unsigned short));  // 1KB

    prep_csq<<<KC, 64, 0, stream>>>(Cp, csq);
    prep_reorder<<<128, 64, 0, stream>>>(Cp, Bf);

    const int ntiles = (N + 15) / 16;  // 12500
    main_kernel<<<GRID, NT, 0, stream>>>(zp, (const uint4*)Bf, csq, (float*)d_out, ntiles);
}